// Round 8
// baseline (54573.706 us; speedup 1.0000x reference)
//
#include <hip/hip_runtime.h>
#include <math.h>

#define B_ 64
#define T_ 600
#define U_ 64
#define V_ 80
#define H_ 512
#define KA_ 10
#define KO_ 20

// padded weight row strides (floats)
#define S0_ 600
#define S12_ 1108
#define NLB_ 64   // blocks per LSTM layer (8 units each)
#define NWB_ 64   // window blocks (1 batch each)

typedef unsigned u32x4 __attribute__((ext_vector_type(4)));

__device__ __forceinline__ float sigmf(float x){ return 1.0f/(1.0f+expf(-x)); }

// --- coherent (cache-bypassing / write-through) primitives ---
__device__ __forceinline__ int coh_load_i32(const int* p){
    int v;
    asm volatile("global_load_dword %0, %1, off sc0 sc1\n\ts_waitcnt vmcnt(0)"
                 : "=v"(v) : "v"(p) : "memory");
    return v;
}
__device__ __forceinline__ void coh_store_u32(unsigned* p, unsigned v){
    asm volatile("global_store_dword %0, %1, off sc0 sc1" :: "v"(p), "v"(v) : "memory");
}
__device__ __forceinline__ void coh_store_u128(unsigned* p, u32x4 v){
    asm volatile("global_store_dwordx4 %0, %1, off sc0 sc1" :: "v"(p), "v"(v) : "memory");
}
__device__ __forceinline__ void spin_ge(int* p, int target){
    while (coh_load_i32(p) < target) __builtin_amdgcn_s_sleep(1);
}
#define BLOCK_WAIT(p, tgt) do { if (threadIdx.x == 0) spin_ge((p), (tgt)); __syncthreads(); } while (0)

__device__ __forceinline__ float blo(unsigned u){ return __uint_as_float(u << 16); }
__device__ __forceinline__ float bhi(unsigned u){ return __uint_as_float(u & 0xffff0000u); }
__device__ __forceinline__ unsigned pack_bf16(float a, float b){
    return ((__float_as_uint(a) + 0x8000u) >> 16) | ((__float_as_uint(b) + 0x8000u) & 0xffff0000u);
}

// ---------------------------------------------------------------------------
// Weight repack (fp32): row r -> padded row:
// [0..2]=stroke, [3]=pad, [4..83]=attn, [84..595]=xprev/Whh, (+[596..1107]=Whh for L1/2)
__global__ __launch_bounds__(64) void k_prep(
    const float* __restrict__ W0ih, const float* __restrict__ W0hh,
    const float* __restrict__ W1ih, const float* __restrict__ W1hh,
    const float* __restrict__ W2ih, const float* __restrict__ W2hh,
    float* __restrict__ wpad)
{
    int r = blockIdx.x;       // 0..6143
    int tid = threadIdx.x;
    if (r < 2048){
        float* dst = wpad + (size_t)r*S0_;
        const float* sih = W0ih + (size_t)r*83;
        const float* shh = W0hh + (size_t)r*512;
        if (tid < 3) dst[tid] = sih[tid];
        if (tid == 3) dst[3] = 0.f;
        for (int v=tid; v<V_; v+=64) dst[4+v] = sih[3+v];
        for (int k=tid; k<H_; k+=64) dst[84+k] = shh[k];
    } else {
        int rr = r - 2048;
        int layer = rr >> 11;
        int row = rr & 2047;
        const float* sih = (layer==0 ? W1ih : W2ih) + (size_t)row*595;
        const float* shh = (layer==0 ? W1hh : W2hh) + (size_t)row*512;
        float* dst = wpad + (size_t)2048*S0_ + ((size_t)layer*2048 + row)*S12_;
        if (tid < 3) dst[tid] = sih[tid];
        if (tid == 3) dst[3] = 0.f;
        for (int v=tid; v<V_; v+=64) dst[4+v] = sih[3+v];
        for (int k=tid; k<H_; k+=64) dst[84+k] = sih[83+k];
        for (int k=tid; k<H_; k+=64) dst[596+k] = shh[k];
    }
}

// 8-value FMA into one gate accumulator from one bf16x8 packet
#define FMA8(W, OFF) do { \
    float4 qa = *(const float4*)((W) + (OFF)); \
    float4 qb = *(const float4*)((W) + (OFF) + 4); \
    A0 += x0*qa.x + x1*qa.y + x2*qa.z + x3*qa.w + x4*qb.x + x5*qb.y + x6*qb.z + x7*qb.w; \
} while (0)

// ---------------------------------------------------------------------------
// Persistent pipelined kernel. Grid 256 x 512:
//   bid [0,64)    : layer0, 8 units each (ub = bid*8)
//   bid [64,128)  : layer1
//   bid [128,192) : layer2
//   bid [192,256) : window, batch wb = bid-192
// h: bf16 pairs, [t][kp][b] uint4 (kp = k/8), FULL history per layer.
// attn: bf16 pairs, [t][b][40] u32, FULL history.
// Producers: LDS-staged COALESCED sc0sc1 write-through -> vmcnt drain -> atomicAdd flag.
// Consumers: bypassing poll -> barrier -> normal cached loads (fresh addresses).
__global__ __launch_bounds__(512, 2) void k_pipe(
    const float* __restrict__ strokes,
    const int*   __restrict__ char_seq,
    const float* __restrict__ char_mask,
    const float* __restrict__ wpad,
    const float* __restrict__ winW, const float* __restrict__ winb,
    const float* __restrict__ b0, const float* __restrict__ b1, const float* __restrict__ b2,
    unsigned* __restrict__ out0b, unsigned* __restrict__ out1b, unsigned* __restrict__ out2b,
    unsigned* __restrict__ attnb, int* __restrict__ sync)
{
    // one-time wipe of stale L2 lines from previous replay / poison
    __builtin_amdgcn_fence(__ATOMIC_ACQUIRE, "agent");

    int* c0 = sync;
    int* c1 = sync + 640;
    int* c2 = sync + 1280;
    int* cw = sync + 1920;

    const int bid = blockIdx.x;
    const int tid = threadIdx.x;
    const int b   = tid & 63;
    const int r   = tid >> 6;          // 0..7

    __shared__ float sh[8][64];
    __shared__ float shh[512];
    __shared__ float pp[30][16];
    __shared__ float sa[KA_], sbv[KA_], sk[KA_], skst[KA_];
    __shared__ float sphi[U_];
    __shared__ float satt[V_];
    __shared__ int   sseq[U_];
    __shared__ float smask[U_];

    if (bid >= 192){
        // ---------------- window role ----------------
        const int wb = bid - 192;
        if (tid < U_){ sseq[tid] = char_seq[wb*U_+tid]; smask[tid] = char_mask[wb*U_+tid]; }
        __syncthreads();
        for (int t=0; t<T_; ++t){
            BLOCK_WAIT(&c0[t], NLB_);
            if (tid < 64){
                uint4 q = ((const uint4*)out0b)[((size_t)t*64 + tid)*64 + wb];
                shh[8*tid+0]=blo(q.x); shh[8*tid+1]=bhi(q.x);
                shh[8*tid+2]=blo(q.y); shh[8*tid+3]=bhi(q.y);
                shh[8*tid+4]=blo(q.z); shh[8*tid+5]=bhi(q.z);
                shh[8*tid+6]=blo(q.w); shh[8*tid+7]=bhi(q.w);
            }
            __syncthreads();
            if (tid < 480){
                int rr = tid >> 4, p = tid & 15;
                const float* wrow = winW + (size_t)rr*H_;
                float acc = 0.f;
                #pragma unroll 8
                for (int i=0; i<32; ++i) acc += shh[p+16*i]*wrow[p+16*i];
                pp[rr][p] = acc;
            }
            __syncthreads();
            if (tid < 30){
                float pv = winb[tid];
                #pragma unroll
                for (int i=0; i<16; ++i) pv += pp[tid][i];
                float e = expf(pv);
                if (tid < KA_) sa[tid] = e;
                else if (tid < 2*KA_) sbv[tid-KA_] = e;
                else {
                    int a2 = tid - 2*KA_;
                    float kn = ((t == 0) ? 0.f : skst[a2]) + e;
                    skst[a2] = kn; sk[a2] = kn;
                }
            }
            __syncthreads();
            if (tid < U_){
                float acc = 0.f;
                #pragma unroll
                for (int a=0; a<KA_; ++a){
                    float d = sk[a] - (float)tid;
                    acc += sa[a]*expf(-sbv[a]*d*d);
                }
                sphi[tid] = acc * smask[tid]*smask[tid];
            }
            __syncthreads();
            if (tid < V_){
                float wv = 0.f;
                for (int u=0; u<U_; ++u) wv += (sseq[u] == tid) ? sphi[u] : 0.f;
                satt[tid] = wv;
            }
            __syncthreads();
            if (tid < 40){
                coh_store_u32(attnb + (size_t)t*2560 + (size_t)wb*40 + tid,
                              pack_bf16(satt[2*tid], satt[2*tid+1]));
                asm volatile("s_waitcnt vmcnt(0)" ::: "memory");
            }
            __syncthreads();
            if (tid == 0) atomicAdd(&cw[t], 1);
        }
        return;
    }

    // ---------------- layer role ----------------
    const int l  = bid >> 6;          // 0,1,2
    const int ub = (bid & 63) * 8;
    const int cu = ub + r;

    const float* wbase; const float* bias_p; size_t wst;
    unsigned* hbo; const unsigned* hbp; int* cself; int* cprev;
    if (l == 0){ wbase = wpad;                                  wst = S0_;  bias_p = b0; hbo = out0b; hbp = nullptr; cself = c0; cprev = nullptr; }
    else if (l == 1){ wbase = wpad + (size_t)2048*S0_;          wst = S12_; bias_p = b1; hbo = out1b; hbp = out0b;  cself = c1; cprev = c0; }
    else { wbase = wpad + (size_t)2048*S0_ + (size_t)2048*S12_; wst = S12_; bias_p = b2; hbo = out2b; hbp = out1b;  cself = c2; cprev = c1; }

    const float* w0 = wbase + (size_t)(0*H_+cu)*wst;
    const float* w1 = wbase + (size_t)(1*H_+cu)*wst;
    const float* w2 = wbase + (size_t)(2*H_+cu)*wst;
    const float* w3 = wbase + (size_t)(3*H_+cu)*wst;

    const float bq0 = bias_p[0*H_+cu];
    const float bq1 = bias_p[1*H_+cu];
    const float bq2 = bias_p[2*H_+cu];
    const float bq3 = bias_p[3*H_+cu];
    float creg = 0.f;

    for (int t=0; t<T_; ++t){
        float a0, a1, a2, a3;
        {
            const float* sr = strokes + ((size_t)b*T_ + t)*3;
            float sx=sr[0], sy=sr[1], sz=sr[2];
            a0 = sx*w0[0] + sy*w0[1] + sz*w0[2];
            a1 = sx*w1[0] + sy*w1[1] + sz*w1[2];
            a2 = sx*w2[0] + sy*w2[1] + sz*w2[2];
            a3 = sx*w3[0] + sy*w3[1] + sz*w3[2];
        }

        if (l == 0){
            if (t > 0){
                BLOCK_WAIT(&c0[t-1], NLB_);
                const uint4* hp = (const uint4*)out0b + (size_t)(t-1)*4096 + b;
                #pragma unroll 4
                for (int kp=0; kp<64; ++kp){
                    uint4 q = hp[(size_t)kp*64];
                    float x0=blo(q.x),x1=bhi(q.x),x2=blo(q.y),x3=bhi(q.y);
                    float x4=blo(q.z),x5=bhi(q.z),x6=blo(q.w),x7=bhi(q.w);
                    int o = 84 + 8*kp;
                    { float A0=a0; FMA8(w0,o); a0=A0; }
                    { float A0=a1; FMA8(w1,o); a1=A0; }
                    { float A0=a2; FMA8(w2,o); a2=A0; }
                    { float A0=a3; FMA8(w3,o); a3=A0; }
                }
                BLOCK_WAIT(&cw[t-1], NWB_);
                const uint4* ap = (const uint4*)(attnb + (size_t)(t-1)*2560 + (size_t)b*40);
                #pragma unroll
                for (int j=0; j<10; ++j){
                    uint4 q = ap[j];
                    float x0=blo(q.x),x1=bhi(q.x),x2=blo(q.y),x3=bhi(q.y);
                    float x4=blo(q.z),x5=bhi(q.z),x6=blo(q.w),x7=bhi(q.w);
                    int o = 4 + 8*j;
                    { float A0=a0; FMA8(w0,o); a0=A0; }
                    { float A0=a1; FMA8(w1,o); a1=A0; }
                    { float A0=a2; FMA8(w2,o); a2=A0; }
                    { float A0=a3; FMA8(w3,o); a3=A0; }
                }
            }
        } else {
            if (tid == 0){
                if (t > 0) spin_ge(&cself[t-1], NLB_);
                spin_ge(&cprev[t], NLB_);
                spin_ge(&cw[t], NWB_);
            }
            __syncthreads();
            const uint4* hc = (const uint4*)hbp + (size_t)t*4096 + b;
            if (t > 0){
                const uint4* ho = (const uint4*)hbo + (size_t)(t-1)*4096 + b;
                #pragma unroll 2
                for (int kp=0; kp<64; ++kp){
                    uint4 qo = ho[(size_t)kp*64];
                    uint4 qc = hc[(size_t)kp*64];
                    {
                        float x0=blo(qo.x),x1=bhi(qo.x),x2=blo(qo.y),x3=bhi(qo.y);
                        float x4=blo(qo.z),x5=bhi(qo.z),x6=blo(qo.w),x7=bhi(qo.w);
                        int o = 596 + 8*kp;
                        { float A0=a0; FMA8(w0,o); a0=A0; }
                        { float A0=a1; FMA8(w1,o); a1=A0; }
                        { float A0=a2; FMA8(w2,o); a2=A0; }
                        { float A0=a3; FMA8(w3,o); a3=A0; }
                    }
                    {
                        float x0=blo(qc.x),x1=bhi(qc.x),x2=blo(qc.y),x3=bhi(qc.y);
                        float x4=blo(qc.z),x5=bhi(qc.z),x6=blo(qc.w),x7=bhi(qc.w);
                        int o = 84 + 8*kp;
                        { float A0=a0; FMA8(w0,o); a0=A0; }
                        { float A0=a1; FMA8(w1,o); a1=A0; }
                        { float A0=a2; FMA8(w2,o); a2=A0; }
                        { float A0=a3; FMA8(w3,o); a3=A0; }
                    }
                }
            } else {
                #pragma unroll 4
                for (int kp=0; kp<64; ++kp){
                    uint4 qc = hc[(size_t)kp*64];
                    float x0=blo(qc.x),x1=bhi(qc.x),x2=blo(qc.y),x3=bhi(qc.y);
                    float x4=blo(qc.z),x5=bhi(qc.z),x6=blo(qc.w),x7=bhi(qc.w);
                    int o = 84 + 8*kp;
                    { float A0=a0; FMA8(w0,o); a0=A0; }
                    { float A0=a1; FMA8(w1,o); a1=A0; }
                    { float A0=a2; FMA8(w2,o); a2=A0; }
                    { float A0=a3; FMA8(w3,o); a3=A0; }
                }
            }
            const uint4* ap = (const uint4*)(attnb + (size_t)t*2560 + (size_t)b*40);
            #pragma unroll
            for (int j=0; j<10; ++j){
                uint4 q = ap[j];
                float x0=blo(q.x),x1=bhi(q.x),x2=blo(q.y),x3=bhi(q.y);
                float x4=blo(q.z),x5=bhi(q.z),x6=blo(q.w),x7=bhi(q.w);
                int o = 4 + 8*j;
                { float A0=a0; FMA8(w0,o); a0=A0; }
                { float A0=a1; FMA8(w1,o); a1=A0; }
                { float A0=a2; FMA8(w2,o); a2=A0; }
                { float A0=a3; FMA8(w3,o); a3=A0; }
            }
        }

        // combine in-register: thread (r,b) owns unit cu
        {
            float gi  = a0 + bq0;
            float gf  = a1 + bq1;
            float gg_ = a2 + bq2;
            float go  = a3 + bq3;
            float cold = (t == 0) ? 0.f : creg;
            float cnew = sigmf(gf)*cold + sigmf(gi)*tanhf(gg_);
            creg = cnew;
            sh[r][b] = sigmf(go)*tanhf(cnew);
        }
        __syncthreads();
        if (tid < 64){
            u32x4 v;
            v.x = pack_bf16(sh[0][tid], sh[1][tid]);
            v.y = pack_bf16(sh[2][tid], sh[3][tid]);
            v.z = pack_bf16(sh[4][tid], sh[5][tid]);
            v.w = pack_bf16(sh[6][tid], sh[7][tid]);
            coh_store_u128(hbo + (size_t)t*16384 + (size_t)(ub>>3)*256 + tid*4, v);
            asm volatile("s_waitcnt vmcnt(0)" ::: "memory");
        }
        __syncthreads();
        if (tid == 0) atomicAdd(&cself[t], 1);
    }
}

// ---------------------------------------------------------------------------
// FC head + output transforms, fused. One block per t. h inputs are bf16 pairs.
__global__ __launch_bounds__(256) void k_fc(
    const unsigned* __restrict__ out0b, const unsigned* __restrict__ out1b, const unsigned* __restrict__ out2b,
    const float* __restrict__ fcW, const float* __restrict__ fcb, float* __restrict__ out)
{
    int t = blockIdx.x; int tid = threadIdx.x;
    int b = tid & 63; int gq = tid >> 6;
    __shared__ float smraw[128*65];   // union: acts[128][65] / fin[121][64]

    float acc[31];
    #pragma unroll
    for (int i=0; i<31; ++i) acc[i] = 0.f;

    const unsigned* hbs[3] = {out0b, out1b, out2b};
    for (int seg=0; seg<3; ++seg){
        const uint4* o = (const uint4*)hbs[seg];
        for (int kc=0; kc<H_; kc+=128){
            int kp0 = kc >> 3;
            __syncthreads();
            #pragma unroll
            for (int rr=0; rr<4; ++rr){
                int idx = tid + 256*rr;          // 0..1023
                int kq  = idx >> 6;              // 0..15
                int bb  = idx & 63;
                uint4 v = o[((size_t)t*64 + kp0 + kq)*64 + bb];
                int kb = kq*8;
                smraw[(kb+0)*65+bb]=blo(v.x); smraw[(kb+1)*65+bb]=bhi(v.x);
                smraw[(kb+2)*65+bb]=blo(v.y); smraw[(kb+3)*65+bb]=bhi(v.y);
                smraw[(kb+4)*65+bb]=blo(v.z); smraw[(kb+5)*65+bb]=bhi(v.z);
                smraw[(kb+6)*65+bb]=blo(v.w); smraw[(kb+7)*65+bb]=bhi(v.w);
            }
            __syncthreads();
            for (int kk=0; kk<128; kk+=4){
                float a0 = smraw[(kk+0)*65+b];
                float a1 = smraw[(kk+1)*65+b];
                float a2 = smraw[(kk+2)*65+b];
                float a3 = smraw[(kk+3)*65+b];
                int K = seg*H_ + kc + kk;
                #pragma unroll
                for (int i=0; i<30; ++i){
                    float4 w = *(const float4*)(fcW + (size_t)(gq+4*i)*1536 + K);
                    acc[i] += a0*w.x + a1*w.y + a2*w.z + a3*w.w;
                }
                if (gq == 0){
                    float4 w = *(const float4*)(fcW + (size_t)120*1536 + K);
                    acc[30] += a0*w.x + a1*w.y + a2*w.z + a3*w.w;
                }
            }
        }
    }
    __syncthreads();
    #pragma unroll
    for (int i=0; i<30; ++i) smraw[(gq+4*i)*64 + b] = acc[i] + fcb[gq+4*i];
    if (gq == 0) smraw[120*64 + b] = acc[30] + fcb[120];
    __syncthreads();

    if (tid < 64){
        size_t bt = (size_t)b*T_ + t;
        float* myu = out + 768000;
        #pragma unroll
        for (int q=0; q<10; ++q){
            float4 v;
            v.x = smraw[(4*q+0)*64+b]; v.y = smraw[(4*q+1)*64+b];
            v.z = smraw[(4*q+2)*64+b]; v.w = smraw[(4*q+3)*64+b];
            *(float4*)(myu + bt*40 + 4*q) = v;
        }
        float* lsg = out + 2304000;
        #pragma unroll
        for (int q=0; q<10; ++q){
            float4 v;
            v.x = smraw[(40+4*q+0)*64+b]; v.y = smraw[(40+4*q+1)*64+b];
            v.z = smraw[(40+4*q+2)*64+b]; v.w = smraw[(40+4*q+3)*64+b];
            *(float4*)(lsg + bt*40 + 4*q) = v;
        }
        float pi[KO_];
        float m = -1e30f;
        #pragma unroll
        for (int ko=0; ko<KO_; ++ko){ pi[ko] = smraw[(80+ko)*64+b]; m = fmaxf(m, pi[ko]); }
        float s = 0.f;
        #pragma unroll
        for (int ko=0; ko<KO_; ++ko) s += expf(pi[ko]-m);
        float lse = m + logf(s);
        #pragma unroll
        for (int q=0; q<5; ++q){
            float4 v;
            v.x = pi[4*q+0]-lse; v.y = pi[4*q+1]-lse; v.z = pi[4*q+2]-lse; v.w = pi[4*q+3]-lse;
            *(float4*)(out + bt*20 + 4*q) = v;
        }
        float* rho = out + 3840000;
        #pragma unroll
        for (int q=0; q<5; ++q){
            float4 v;
            v.x = tanhf(smraw[(100+4*q+0)*64+b]); v.y = tanhf(smraw[(100+4*q+1)*64+b]);
            v.z = tanhf(smraw[(100+4*q+2)*64+b]); v.w = tanhf(smraw[(100+4*q+3)*64+b]);
            *(float4*)(rho + bt*20 + 4*q) = v;
        }
        out[4608000 + bt] = 1.f/(1.f + expf(smraw[120*64+b]));
    }
}

// ---------------------------------------------------------------------------
extern "C" void kernel_launch(void* const* d_in, const int* in_sizes, int n_in,
                              void* d_out, int out_size, void* d_ws, size_t ws_size,
                              hipStream_t stream)
{
    const int*   char_seq  = (const int*)  d_in[0];
    const float* char_mask = (const float*)d_in[1];
    const float* strokes   = (const float*)d_in[2];
    const float* W0ih = (const float*)d_in[4];
    const float* W0hh = (const float*)d_in[5];
    const float* b0   = (const float*)d_in[6];
    const float* winW = (const float*)d_in[7];
    const float* winb = (const float*)d_in[8];
    const float* W1ih = (const float*)d_in[9];
    const float* W1hh = (const float*)d_in[10];
    const float* b1   = (const float*)d_in[11];
    const float* W2ih = (const float*)d_in[12];
    const float* W2hh = (const float*)d_in[13];
    const float* b2   = (const float*)d_in[14];
    const float* fcW  = (const float*)d_in[15];
    const float* fcb  = (const float*)d_in[16];

    unsigned* out0b = (unsigned*)d_ws;             // [600][64][64] uint4 = 9,830,400 u32
    unsigned* out1b = out0b + 9830400;
    unsigned* out2b = out1b + 9830400;
    unsigned* attnb = out2b + 9830400;             // [600][64][40] u32 = 1,536,000
    float*    wpad  = (float*)(attnb + 1536000);   // 5,767,168 fl
    int*      sync  = (int*)(wpad + 5767168);      // 2,560 ints (total ~147 MB)

    (void)hipMemsetAsync(sync, 0, 2560*sizeof(int), stream);

    hipLaunchKernelGGL(k_prep, dim3(6144), dim3(64), 0, stream,
        W0ih, W0hh, W1ih, W1hh, W2ih, W2hh, wpad);

    hipLaunchKernelGGL(k_pipe, dim3(256), dim3(512), 0, stream,
        strokes, char_seq, char_mask, wpad, winW, winb, b0, b1, b2,
        out0b, out1b, out2b, attnb, sync);

    hipLaunchKernelGGL(k_fc, dim3(600), dim3(256), 0, stream,
        out0b, out1b, out2b, fcW, fcb, (float*)d_out);
}